// Round 10
// baseline (321.742 us; speedup 1.0000x reference)
//
#include <hip/hip_runtime.h>
#include <hip/hip_bf16.h>

typedef __attribute__((ext_vector_type(8))) short bf16x8;   // 8 bf16 = 4 VGPRs
typedef __attribute__((ext_vector_type(4))) float f32x4;

#define WDIM 512
#define CIN 128
#define COUT 128
#define NRES 32
#define NSP 32768          // 32^3
#define NTAPS 27

#define ROWB 2112          // LDS bytes per (z,y) halo row: 32 hx * 64 B + 64 B zero col
#define LDSROWS 16         // 4 hz * 4 hy
#define BUFB (LDSROWS * ROWB)   // 33792 B per buffer; double-buffered

// ws layout (bytes):
//   [0,4096)        styles f32[8][128] (unused scratch now)
//   [4096,8192)     zeropad (zeroed by k_wmod block 0)
//   [8192,+64 MiB)  xt bf16 [8][4cc][32768 sp][32 cin]
//   [+64MiB, +6.75MiB) wmod bf16 [8][cc][128 cout][27 tap][32 cin]
#define ZP_OFF 4096
#define XT_OFF 8192
#define WM_OFF (8192 + 67108864)

typedef __attribute__((address_space(1))) const unsigned int gu32;
typedef __attribute__((address_space(3))) unsigned int lu32;

// ---- kernel 1: styles (in-block) + modulate/demodulate -> wmod[b][cc][cout][tap][cin32]
//      block 0 also zeroes the 4 KB zeropad region ----
__global__ __launch_bounds__(256)
void k_wmod(const float* __restrict__ w,
            const float* __restrict__ aw,
            const float* __restrict__ ab,
            const float* __restrict__ weight,
            float* __restrict__ zeropad,
            __hip_bfloat16* __restrict__ wmod) {
  int b = blockIdx.x >> 7;
  int co = blockIdx.x & 127;
  int tid = threadIdx.x;   // 256
  if (blockIdx.x == 0) {
#pragma unroll
    for (int i = 0; i < 4; i++) zeropad[i * 256 + tid] = 0.f;
  }
  __shared__ float stp[256];
  __shared__ float st[CIN];
  __shared__ float red[4];
  // styles: thread (c, half) does a 256-elem partial dot
  {
    int c = tid & 127, half = tid >> 7;
    const float4* wr = (const float4*)(w + (size_t)b * WDIM + half * 256);
    const float4* ar = (const float4*)(aw + (size_t)c * WDIM + half * 256);
    float s = 0.f;
#pragma unroll 8
    for (int k = 0; k < 64; k++) {
      float4 wv = wr[k], av = ar[k];
      s += wv.x * av.x + wv.y * av.y + wv.z * av.z + wv.w * av.w;
    }
    stp[tid] = s;
  }
  __syncthreads();
  if (tid < 128)
    st[tid] = (stp[tid] + stp[tid + 128]) * 0.04419417382415922f + ab[tid];
  __syncthreads();
  const float* wr = weight + (size_t)co * (CIN * NTAPS);  // [cin][27] for this cout
  float ss = 0.f;
  for (int o = tid; o < CIN * NTAPS; o += 256) {
    float v = wr[o] * st[o / NTAPS];
    ss += v * v;
  }
#pragma unroll
  for (int off = 32; off > 0; off >>= 1) ss += __shfl_down(ss, off);
  if ((tid & 63) == 0) red[tid >> 6] = ss;
  __syncthreads();
  float d = rsqrtf(red[0] + red[1] + red[2] + red[3] + 1e-8f);
  for (int o = tid; o < CIN * NTAPS; o += 256) {
    int t = o >> 7;
    int cin = o & 127;
    float v = wr[cin * NTAPS + t] * st[cin] * d;
    int cc = cin >> 5, cl = cin & 31;
    wmod[((((size_t)(b * 4 + cc) * COUT + co) * NTAPS + t) << 5) + cl] =
        __float2bfloat16(v);
  }
}

// ---- kernel 2: x f32 [b][cin][sp] -> xt bf16 [b][cc][sp][cin32] ----
__global__ __launch_bounds__(256)
void k_xt(const float* __restrict__ x, __hip_bfloat16* __restrict__ xt) {
  __shared__ __align__(16) float ts[32][257];   // 32.9 KB, pad -> 2-way max
  int t = threadIdx.x;
  int blk = blockIdx.x;            // 8 b * 4 cc * 128 spchunks
  int b = blk >> 9, cc = (blk >> 7) & 3, sp0 = (blk & 127) << 8;
  const float* xb = x + (size_t)b * CIN * NSP + (size_t)cc * 32 * NSP + sp0;
#pragma unroll
  for (int i = 0; i < 8; i++) {
    int q = i * 256 + t;
    int cin = q >> 6, f4 = q & 63;
    float4 v = *(const float4*)(xb + (size_t)cin * NSP + f4 * 4);
    *(float4*)&ts[cin][f4 * 4] = v;
  }
  __syncthreads();
  __hip_bfloat16* ob = xt + ((size_t)(b * 4 + cc) * NSP + sp0) * 32;
#pragma unroll
  for (int j = 0; j < 4; j++) {
    int chunk = j * 256 + t;
    int sp_l = chunk >> 2, q = chunk & 3;
    union { bf16x8 v; __hip_bfloat16 h[8]; } u;
#pragma unroll
    for (int k = 0; k < 8; k++) u.h[k] = __float2bfloat16(ts[q * 8 + k][sp_l]);
    *(bf16x8*)(ob + (size_t)sp_l * 32 + q * 8) = u.v;
  }
}

// ---------------- kernel 3: implicit-GEMM conv + bias + lrelu*sqrt(2) ----------------
// 256 thr = 4 waves = 2 cout-halves x 2 z-halves. Wave = 64 cout x 64 sp
// (acc 4mi x 4ni). B ds_read dup = 2 (16 b128/block/tap); A dup = 2 but the two
// sp-half waves read IDENTICAL A addrs within ~1 tap in the SAME block -> L1 dedups
// (32 KB = 4 taps of A). LDS dbuf, STAGE(cc+1) at tap 1, b=blk&7 XCD pinning.
__global__ __launch_bounds__(256, 2)
void k_conv(const char* __restrict__ ws,
            const float* __restrict__ bias,
            float* __restrict__ out) {
  extern __shared__ __align__(16) char xs[];   // 2 * BUFB

  int tid = threadIdx.x;
  int lane = tid & 63, w = tid >> 6;
  int l15 = lane & 15, g = lane >> 4;
  int w2 = w >> 1, wz = w & 1;     // cout-half, z-half
  int blk = blockIdx.x;
  int b = blk & 7;                 // one batch per XCD (wmod/xt L2 locality)
  int tile = blk >> 3;             // 16 tz * 16 ty, sequential per XCD
  int z0 = (tile >> 4) * 2, y0 = (tile & 15) * 2;

  // zero column init, both buffers: 16 rows x 64 B at row offset 2048
  {
    int r16 = tid >> 4, c16 = (tid & 15) * 4;
    *(int*)&xs[r16 * ROWB + 2048 + c16] = 0;
    *(int*)&xs[BUFB + r16 * ROWB + 2048 + c16] = 0;
  }

  // ---- staging tables: 2048 16-B chunks per cc, 8 iters x 256 thr ----
  int soff[8], sdst[8], svalid[8];
#pragma unroll
  for (int i = 0; i < 8; i++) {
    int c = i * 256 + tid;
    int zy = c >> 7;                       // wave-uniform
    int hz = zy >> 2, hy = zy & 3;
    int zz = z0 + hz - 1, yy = y0 + hy - 1;
    svalid[i] = ((unsigned)zz < NRES) & ((unsigned)yy < NRES);
    int p = c & 127, hx = p >> 2, pos = p & 3;
    int q = pos ^ ((hx >> 1) & 3);         // pre-swizzled global source (rule #21)
    soff[i] = (zz * 1024 + yy * 32 + hx) * 4 + q;   // 16-B units within xt[b][cc]
    sdst[i] = zy * ROWB + (p >> 6) * 1024;          // linear wave-uniform LDS dest
  }

  // ---- fragment LDS addrs: vaddr[ni][tx]; ni = dy*2+dxh; OOB x -> zero col ----
  int vaddr[4][3];
#pragma unroll
  for (int ni = 0; ni < 4; ni++) {
    int row = wz * 4 + (ni >> 1);                // (wz+tz)*4+(dy+ty) = this + lit
    int dx = (ni & 1) * 16 + l15;
#pragma unroll
    for (int tx = 0; tx < 3; tx++) {
      int hx = dx + tx - 1;
      int hxc = ((unsigned)hx > 31u) ? 32 : hx;
      int pos = g ^ ((hxc >> 1) & 3);
      vaddr[ni][tx] = row * ROWB + hxc * 64 + pos * 16;
    }
  }

  // ---- A chunk bases: chunk idx = ((b*4+cc)*128 + cout)*108 + tap*4 + g ----
  const bf16x8* ap = (const bf16x8*)(ws + WM_OFF);
  int abase[4];
#pragma unroll
  for (int mi = 0; mi < 4; mi++)
    abase[mi] = (w2 * 64 + mi * 16 + l15) * 108 + g;

  f32x4 acc[4][4];
#pragma unroll
  for (int mi = 0; mi < 4; mi++)
#pragma unroll
    for (int ni = 0; ni < 4; ni++) acc[mi][ni] = (f32x4){0.f, 0.f, 0.f, 0.f};

  const char* zpg = ws + ZP_OFF;
  const char* xtb = ws + XT_OFF + (size_t)b * (4 * NSP * 64);

  auto stage = [&](char* dst, const char* xtc) {
#pragma unroll
    for (int i = 0; i < 8; i++) {
      const char* src = svalid[i] ? (xtc + ((size_t)(unsigned)soff[i] << 4))
                                  : (zpg + lane * 16);
      __builtin_amdgcn_global_load_lds((gu32*)src, (lu32*)(dst + sdst[i]), 16, 0, 0);
    }
  };

  // prologue: stage cc=0 into buf0; barrier drains it (once) + zero-col visible
  stage(xs, xtb);
  __syncthreads();

#pragma unroll 1
  for (int cc = 0; cc < 4; cc++) {
    char* cur = xs + (cc & 1) * BUFB;
    int sab = ((b * 4 + cc) * 128) * 108;
    int abc[4];
#pragma unroll
    for (int mi = 0; mi < 4; mi++) abc[mi] = sab + abase[mi];

    bf16x8 A[2][4], B[2][4];
#pragma unroll
    for (int mi = 0; mi < 4; mi++) A[0][mi] = ap[abc[mi]];
#pragma unroll
    for (int j = 0; j < 4; j++) B[0][j] = *(const bf16x8*)(cur + vaddr[j][0]);

#pragma unroll
    for (int t = 0; t < NTAPS; t++) {
      const int s = t & 1, ns = s ^ 1;
      const int t1 = t + 1;
      // A(t+1) issue at top of tap t (full-tap prefetch; L1 dedups across sp-waves)
      if (t < NTAPS - 1) {
#pragma unroll
        for (int mi = 0; mi < 4; mi++) A[ns][mi] = ap[abc[mi] + t1 * 4];
      }
      // STAGE(cc+1) once, at tap 1 (A(2) issued before it -> its wait is free;
      // A(3) waited ~2 taps after STAGE issue -> latency covered)
      if (t == 1 && cc < 3) {
        __builtin_amdgcn_sched_barrier(0);
        stage(xs + ((cc + 1) & 1) * BUFB, xtb + (size_t)(cc + 1) * (NSP * 64));
        __builtin_amdgcn_sched_barrier(0);
      }
      // B(t+1) full-tap prefetch (4 reads)
      if (t < NTAPS - 1) {
        const int tx1 = t1 % 3;
        const int lit1 = ((t1 / 9) * 4 + (t1 / 3) % 3) * ROWB;
#pragma unroll
        for (int j = 0; j < 4; j++)
          B[ns][j] = *(const bf16x8*)(cur + vaddr[j][tx1] + lit1);
      }
      __builtin_amdgcn_s_setprio(1);
#pragma unroll
      for (int mi = 0; mi < 4; mi++) {
        acc[mi][0] = __builtin_amdgcn_mfma_f32_16x16x32_bf16(A[s][mi], B[s][0], acc[mi][0], 0, 0, 0);
        acc[mi][1] = __builtin_amdgcn_mfma_f32_16x16x32_bf16(A[s][mi], B[s][1], acc[mi][1], 0, 0, 0);
        acc[mi][2] = __builtin_amdgcn_mfma_f32_16x16x32_bf16(A[s][mi], B[s][2], acc[mi][2], 0, 0, 0);
        acc[mi][3] = __builtin_amdgcn_mfma_f32_16x16x32_bf16(A[s][mi], B[s][3], acc[mi][3], 0, 0, 0);
      }
      __builtin_amdgcn_s_setprio(0);
    }
    if (cc < 3) __syncthreads();   // staged loads ~25 taps old -> drain ~free
  }

  // epilogue: cout = w2*64 + mi*16 + g*4 + r ; sp = (z0+wz, y0+dy, dx)
  size_t ob = ((size_t)(b * COUT + w2 * 64 + g * 4)) * NSP +
              (size_t)(z0 + wz) * 1024 + (size_t)y0 * 32;
#pragma unroll
  for (int mi = 0; mi < 4; mi++) {
    float4 bsv = *(const float4*)(bias + w2 * 64 + mi * 16 + g * 4);
    float bs[4] = {bsv.x, bsv.y, bsv.z, bsv.w};
#pragma unroll
    for (int ni = 0; ni < 4; ni++) {
      int spo = (ni >> 1) * 32 + (ni & 1) * 16 + l15;
#pragma unroll
      for (int r = 0; r < 4; r++) {
        float v = acc[mi][ni][r] + bs[r];
        v = (v >= 0.f ? v : v * 0.2f) * 1.41421356237309515f;
        out[ob + (size_t)(mi * 16 + r) * NSP + spo] = v;
      }
    }
  }
}

extern "C" void kernel_launch(void* const* d_in, const int* in_sizes, int n_in,
                              void* d_out, int out_size, void* d_ws, size_t ws_size,
                              hipStream_t stream) {
  const float* x      = (const float*)d_in[0];
  const float* w      = (const float*)d_in[1];
  const float* weight = (const float*)d_in[2];
  const float* aw     = (const float*)d_in[3];
  const float* ab     = (const float*)d_in[4];
  const float* bias   = (const float*)d_in[5];
  float* out = (float*)d_out;

  float* zeropad = (float*)((char*)d_ws + ZP_OFF);
  __hip_bfloat16* xt = (__hip_bfloat16*)((char*)d_ws + XT_OFF);
  __hip_bfloat16* wmod = (__hip_bfloat16*)((char*)d_ws + WM_OFF);

  k_wmod<<<8 * 128, 256, 0, stream>>>(w, aw, ab, weight, zeropad, wmod);
  k_xt<<<8 * 4 * 128, 256, 0, stream>>>(x, xt);
  k_conv<<<8 * 256, 256, 2 * BUFB, stream>>>((const char*)d_ws, bias, out);
}

// Round 11
// 259.963 us; speedup vs baseline: 1.2376x; 1.2376x over previous
//
#include <hip/hip_runtime.h>
#include <hip/hip_bf16.h>

typedef __attribute__((ext_vector_type(8))) short bf16x8;   // 8 bf16 = 4 VGPRs
typedef __attribute__((ext_vector_type(4))) float f32x4;

#define WDIM 512
#define CIN 128
#define COUT 128
#define NRES 32
#define NSP 32768          // 32^3
#define NTAPS 27

#define ROWB 2112          // LDS bytes per (z,y) halo row: 32 hx * 64 B + 64 B zero col
#define LDSROWS 16         // 4 hz * 4 hy
#define BUFB (LDSROWS * ROWB)   // 33792 B per buffer; double-buffered

// ws layout (bytes):
//   [0,4096)        scratch
//   [4096,8192)     zeropad (zeroed by k_wmod block 0)
//   [8192,+64 MiB)  xt bf16 [8][4cc][32768 sp][32 cin]
//   [+64MiB, +6.75MiB) wmod bf16 [8][cc][128 cout][27 tap][32 cin]
#define ZP_OFF 4096
#define XT_OFF 8192
#define WM_OFF (8192 + 67108864)

typedef __attribute__((address_space(1))) const unsigned int gu32;
typedef __attribute__((address_space(3))) unsigned int lu32;

// ---- kernel 1: styles (in-block) + modulate/demodulate -> wmod[b][cc][cout][tap][cin32]
__global__ __launch_bounds__(256)
void k_wmod(const float* __restrict__ w,
            const float* __restrict__ aw,
            const float* __restrict__ ab,
            const float* __restrict__ weight,
            float* __restrict__ zeropad,
            __hip_bfloat16* __restrict__ wmod) {
  int b = blockIdx.x >> 7;
  int co = blockIdx.x & 127;
  int tid = threadIdx.x;   // 256
  if (blockIdx.x == 0) {
#pragma unroll
    for (int i = 0; i < 4; i++) zeropad[i * 256 + tid] = 0.f;
  }
  __shared__ float stp[256];
  __shared__ float st[CIN];
  __shared__ float red[4];
  {
    int c = tid & 127, half = tid >> 7;
    const float4* wr = (const float4*)(w + (size_t)b * WDIM + half * 256);
    const float4* ar = (const float4*)(aw + (size_t)c * WDIM + half * 256);
    float s = 0.f;
#pragma unroll 8
    for (int k = 0; k < 64; k++) {
      float4 wv = wr[k], av = ar[k];
      s += wv.x * av.x + wv.y * av.y + wv.z * av.z + wv.w * av.w;
    }
    stp[tid] = s;
  }
  __syncthreads();
  if (tid < 128)
    st[tid] = (stp[tid] + stp[tid + 128]) * 0.04419417382415922f + ab[tid];
  __syncthreads();
  const float* wr = weight + (size_t)co * (CIN * NTAPS);  // [cin][27] for this cout
  float ss = 0.f;
  for (int o = tid; o < CIN * NTAPS; o += 256) {
    float v = wr[o] * st[o / NTAPS];
    ss += v * v;
  }
#pragma unroll
  for (int off = 32; off > 0; off >>= 1) ss += __shfl_down(ss, off);
  if ((tid & 63) == 0) red[tid >> 6] = ss;
  __syncthreads();
  float d = rsqrtf(red[0] + red[1] + red[2] + red[3] + 1e-8f);
  for (int o = tid; o < CIN * NTAPS; o += 256) {
    int t = o >> 7;
    int cin = o & 127;
    float v = wr[cin * NTAPS + t] * st[cin] * d;
    int cc = cin >> 5, cl = cin & 31;
    wmod[((((size_t)(b * 4 + cc) * COUT + co) * NTAPS + t) << 5) + cl] =
        __float2bfloat16(v);
  }
}

// ---- kernel 2: x f32 [b][cin][sp] -> xt bf16 [b][cc][sp][cin32] ----
__global__ __launch_bounds__(256)
void k_xt(const float* __restrict__ x, __hip_bfloat16* __restrict__ xt) {
  __shared__ __align__(16) float ts[32][257];   // 32.9 KB, pad -> 2-way max
  int t = threadIdx.x;
  int blk = blockIdx.x;            // 8 b * 4 cc * 128 spchunks
  int b = blk >> 9, cc = (blk >> 7) & 3, sp0 = (blk & 127) << 8;
  const float* xb = x + (size_t)b * CIN * NSP + (size_t)cc * 32 * NSP + sp0;
#pragma unroll
  for (int i = 0; i < 8; i++) {
    int q = i * 256 + t;
    int cin = q >> 6, f4 = q & 63;
    float4 v = *(const float4*)(xb + (size_t)cin * NSP + f4 * 4);
    *(float4*)&ts[cin][f4 * 4] = v;
  }
  __syncthreads();
  __hip_bfloat16* ob = xt + ((size_t)(b * 4 + cc) * NSP + sp0) * 32;
#pragma unroll
  for (int j = 0; j < 4; j++) {
    int chunk = j * 256 + t;
    int sp_l = chunk >> 2, q = chunk & 3;
    union { bf16x8 v; __hip_bfloat16 h[8]; } u;
#pragma unroll
    for (int k = 0; k < 8; k++) u.h[k] = __float2bfloat16(ts[q * 8 + k][sp_l]);
    *(bf16x8*)(ob + (size_t)sp_l * 32 + q * 8) = u.v;
  }
}

// ---------------- kernel 3: implicit-GEMM conv + bias + lrelu*sqrt(2) ----------------
// R9 structure (62% MfmaUtil): 256 thr = 4 waves, each wave = one 32-cout quarter x
// FULL 128 sp (16 MFMA per 2 A-chunks per tap = 8:1 MFMA:A ratio). LDS dbuf.
// NEW: A pipelined 4 taps deep — A(0..3) issued BEFORE STAGE at cc top (vmcnt
// in-order: their waits never drain staging); A(t+4) issued at bottom of tap t
// (~3-tap = 770 cy cover vs ~225 cy L2). First post-stage A-wait = tap 4, when
// staging is >=1000 cy old -> drain free. b = blk&7 pins one batch per XCD.
__global__ __launch_bounds__(256, 2)
void k_conv(const char* __restrict__ ws,
            const float* __restrict__ bias,
            float* __restrict__ out) {
  extern __shared__ __align__(16) char xs[];   // 2 * BUFB

  int tid = threadIdx.x;
  int lane = tid & 63, w = tid >> 6;
  int l15 = lane & 15, g = lane >> 4;
  int blk = blockIdx.x;
  int b = blk & 7;                 // one batch per XCD (wmod/xt L2 locality)
  int tile = blk >> 3;             // 16 tz * 16 ty, sequential per XCD
  int z0 = (tile >> 4) * 2, y0 = (tile & 15) * 2;

  // zero column init, both buffers: 16 rows x 64 B at row offset 2048
  {
    int r16 = tid >> 4, c16 = (tid & 15) * 4;
    *(int*)&xs[r16 * ROWB + 2048 + c16] = 0;
    *(int*)&xs[BUFB + r16 * ROWB + 2048 + c16] = 0;
  }

  // ---- staging tables: 2048 16-B chunks per cc, 8 iters x 256 thr ----
  int soff[8], sdst[8], svalid[8];
#pragma unroll
  for (int i = 0; i < 8; i++) {
    int c = i * 256 + tid;
    int zy = c >> 7;                       // wave-uniform
    int hz = zy >> 2, hy = zy & 3;
    int zz = z0 + hz - 1, yy = y0 + hy - 1;
    svalid[i] = ((unsigned)zz < NRES) & ((unsigned)yy < NRES);
    int p = c & 127, hx = p >> 2, pos = p & 3;
    int q = pos ^ ((hx >> 1) & 3);         // pre-swizzled global source (rule #21)
    soff[i] = (zz * 1024 + yy * 32 + hx) * 4 + q;   // 16-B units within xt[b][cc]
    sdst[i] = zy * ROWB + (p >> 6) * 1024;          // linear wave-uniform LDS dest
  }

  // ---- fragment LDS addrs: vaddr[ni][tx], OOB x -> zero column (hx=32) ----
  int vaddr[8][3];
#pragma unroll
  for (int ni = 0; ni < 8; ni++) {
    int row = (ni >> 2) * 4 + ((ni >> 1) & 1);   // dz*4 + dy
    int dx = (ni & 1) * 16 + l15;
#pragma unroll
    for (int tx = 0; tx < 3; tx++) {
      int hx = dx + tx - 1;
      int hxc = ((unsigned)hx > 31u) ? 32 : hx;
      int pos = g ^ ((hxc >> 1) & 3);
      vaddr[ni][tx] = row * ROWB + hxc * 64 + pos * 16;
    }
  }

  // ---- A chunk bases: chunk idx = ((b*4+cc)*128 + cout)*108 + tap*4 + g ----
  const bf16x8* ap = (const bf16x8*)(ws + WM_OFF);
  int abase[2];
#pragma unroll
  for (int mi = 0; mi < 2; mi++)
    abase[mi] = (w * 32 + mi * 16 + l15) * 108 + g;

  f32x4 acc[2][8];
#pragma unroll
  for (int mi = 0; mi < 2; mi++)
#pragma unroll
    for (int ni = 0; ni < 8; ni++) acc[mi][ni] = (f32x4){0.f, 0.f, 0.f, 0.f};

  const char* zpg = ws + ZP_OFF;
  const char* xtb = ws + XT_OFF + (size_t)b * (4 * NSP * 64);

  auto stage = [&](char* dst, const char* xtc) {
#pragma unroll
    for (int i = 0; i < 8; i++) {
      const char* src = svalid[i] ? (xtc + ((size_t)(unsigned)soff[i] << 4))
                                  : (zpg + lane * 16);
      __builtin_amdgcn_global_load_lds((gu32*)src, (lu32*)(dst + sdst[i]), 16, 0, 0);
    }
  };

  // prologue: stage cc=0 into buf0; barrier drains it (once) + zero-col visible
  stage(xs, xtb);
  __syncthreads();

#pragma unroll 1
  for (int cc = 0; cc < 4; cc++) {
    char* cur = xs + (cc & 1) * BUFB;
    int sab = ((b * 4 + cc) * 128) * 108;
    int abc0 = sab + abase[0], abc1 = sab + abase[1];

    bf16x8 A[4][2], B[2][8];
    // deep A prologue: taps 0..3 (8 loads) issued BEFORE STAGE -> their vmcnt
    // waits count only newer A's, never force the staging drain
#pragma unroll
    for (int pt = 0; pt < 4; pt++) {
      A[pt][0] = ap[abc0 + pt * 4];
      A[pt][1] = ap[abc1 + pt * 4];
    }
#pragma unroll
    for (int j = 0; j < 8; j++) B[0][j] = *(const bf16x8*)(cur + vaddr[j][0]);
    __builtin_amdgcn_sched_barrier(0);     // pin: prologue loads before staging
    if (cc < 3)
      stage(xs + ((cc + 1) & 1) * BUFB, xtb + (size_t)(cc + 1) * (NSP * 64));
    __builtin_amdgcn_sched_barrier(0);     // pin: staging before tap loop

#pragma unroll
    for (int t = 0; t < NTAPS; t++) {
      const int s = t & 3;                 // A slot (4-deep)
      const int sb = t & 1, nsb = sb ^ 1;  // B slot (2-deep)
      // B(t+1) full-tap prefetch
      if (t < NTAPS - 1) {
        const int t1 = t + 1;
        const int tx1 = t1 % 3;
        const int lit1 = ((t1 / 9) * 4 + (t1 / 3) % 3) * ROWB;
#pragma unroll
        for (int j = 0; j < 8; j++)
          B[nsb][j] = *(const bf16x8*)(cur + vaddr[j][tx1] + lit1);
      }
      __builtin_amdgcn_s_setprio(1);
#pragma unroll
      for (int mi = 0; mi < 2; mi++) {
        acc[mi][0] = __builtin_amdgcn_mfma_f32_16x16x32_bf16(A[s][mi], B[sb][0], acc[mi][0], 0, 0, 0);
        acc[mi][1] = __builtin_amdgcn_mfma_f32_16x16x32_bf16(A[s][mi], B[sb][1], acc[mi][1], 0, 0, 0);
        acc[mi][2] = __builtin_amdgcn_mfma_f32_16x16x32_bf16(A[s][mi], B[sb][2], acc[mi][2], 0, 0, 0);
        acc[mi][3] = __builtin_amdgcn_mfma_f32_16x16x32_bf16(A[s][mi], B[sb][3], acc[mi][3], 0, 0, 0);
        acc[mi][4] = __builtin_amdgcn_mfma_f32_16x16x32_bf16(A[s][mi], B[sb][4], acc[mi][4], 0, 0, 0);
        acc[mi][5] = __builtin_amdgcn_mfma_f32_16x16x32_bf16(A[s][mi], B[sb][5], acc[mi][5], 0, 0, 0);
        acc[mi][6] = __builtin_amdgcn_mfma_f32_16x16x32_bf16(A[s][mi], B[sb][6], acc[mi][6], 0, 0, 0);
        acc[mi][7] = __builtin_amdgcn_mfma_f32_16x16x32_bf16(A[s][mi], B[sb][7], acc[mi][7], 0, 0, 0);
      }
      __builtin_amdgcn_s_setprio(0);
      // A(t+4) issue at bottom of tap t into slot s (just consumed); ~3-tap cover
      if (t + 4 < NTAPS) {
        A[s][0] = ap[abc0 + (t + 4) * 4];
        A[s][1] = ap[abc1 + (t + 4) * 4];
      }
    }
    if (cc < 3) __syncthreads();   // staged loads ~27 taps old -> drain free
  }

  // epilogue: cout = w*32 + mi*16 + g*4 + r ; sp = (z0+dz, y0+dy, dx)
  size_t ob = ((size_t)(b * COUT + w * 32 + g * 4)) * NSP +
              (size_t)z0 * 1024 + (size_t)y0 * 32;
#pragma unroll
  for (int mi = 0; mi < 2; mi++) {
    float4 bsv = *(const float4*)(bias + w * 32 + mi * 16 + g * 4);
    float bs[4] = {bsv.x, bsv.y, bsv.z, bsv.w};
#pragma unroll
    for (int ni = 0; ni < 8; ni++) {
      int spo = (ni >> 2) * 1024 + ((ni >> 1) & 1) * 32 + (ni & 1) * 16 + l15;
#pragma unroll
      for (int r = 0; r < 4; r++) {
        float v = acc[mi][ni][r] + bs[r];
        v = (v >= 0.f ? v : v * 0.2f) * 1.41421356237309515f;
        out[ob + (size_t)(mi * 16 + r) * NSP + spo] = v;
      }
    }
  }
}

extern "C" void kernel_launch(void* const* d_in, const int* in_sizes, int n_in,
                              void* d_out, int out_size, void* d_ws, size_t ws_size,
                              hipStream_t stream) {
  const float* x      = (const float*)d_in[0];
  const float* w      = (const float*)d_in[1];
  const float* weight = (const float*)d_in[2];
  const float* aw     = (const float*)d_in[3];
  const float* ab     = (const float*)d_in[4];
  const float* bias   = (const float*)d_in[5];
  float* out = (float*)d_out;

  float* zeropad = (float*)((char*)d_ws + ZP_OFF);
  __hip_bfloat16* xt = (__hip_bfloat16*)((char*)d_ws + XT_OFF);
  __hip_bfloat16* wmod = (__hip_bfloat16*)((char*)d_ws + WM_OFF);

  k_wmod<<<8 * 128, 256, 0, stream>>>(w, aw, ab, weight, zeropad, wmod);
  k_xt<<<8 * 4 * 128, 256, 0, stream>>>(x, xt);
  k_conv<<<8 * 256, 256, 2 * BUFB, stream>>>((const char*)d_ws, bias, out);
}

// Round 12
// 237.024 us; speedup vs baseline: 1.3574x; 1.0968x over previous
//
#include <hip/hip_runtime.h>
#include <hip/hip_bf16.h>

typedef __attribute__((ext_vector_type(8))) short bf16x8;   // 8 bf16 = 4 VGPRs
typedef __attribute__((ext_vector_type(4))) float f32x4;

#define WDIM 512
#define CIN 128
#define COUT 128
#define NRES 32
#define NSP 32768          // 32^3
#define NTAPS 27

#define ROWB 2112          // LDS bytes per (z,y) halo row: 32 hx * 64 B + 64 B zero col
#define LDSROWS 16         // 4 hz * 4 hy
#define BUFB (LDSROWS * ROWB)   // 33792 B per buffer; double-buffered

// ws layout (bytes):
//   [0,4096)        styles f32[8][128]
//   [4096,8192)     zeropad (zeroed by k_styles)
//   [8192,+64 MiB)  xt bf16 [8][4cc][32768 sp][32 cin]
//   [+64MiB, +6.75MiB) wmod bf16 [8][cc][128 cout][27 tap][32 cin]
#define ZP_OFF 4096
#define XT_OFF 8192
#define WM_OFF (8192 + 67108864)

typedef __attribute__((address_space(1))) const unsigned int gu32;
typedef __attribute__((address_space(3))) unsigned int lu32;

// ---------------- kernel 1: styles + zero the pad region ----------------
__global__ void k_styles(const float* __restrict__ w,
                         const float* __restrict__ aw,
                         const float* __restrict__ ab,
                         float* __restrict__ styles,
                         float* __restrict__ zeropad) {
  int b = blockIdx.x;      // 8
  int c = threadIdx.x;     // 128
  if (b == 0) {
#pragma unroll
    for (int i = 0; i < 8; i++) zeropad[i * 128 + c] = 0.f;  // 4096 B
  }
  const float4* wr = (const float4*)(w + (size_t)b * WDIM);
  const float4* ar = (const float4*)(aw + (size_t)c * WDIM);
  float s = 0.f;
#pragma unroll 8
  for (int k = 0; k < WDIM / 4; k++) {
    float4 wv = wr[k], av = ar[k];
    s += wv.x * av.x + wv.y * av.y + wv.z * av.z + wv.w * av.w;
  }
  styles[b * CIN + c] = s * 0.04419417382415922f + ab[c];  // 1/sqrt(512)
}

// ---- kernel 2: modulate+demodulate -> bf16 wmod[b][cc][cout][tap][cin32] ----
__global__ void k_wmod(const float* __restrict__ weight,
                       const float* __restrict__ styles,
                       __hip_bfloat16* __restrict__ wmod) {
  int b = blockIdx.x >> 7;
  int co = blockIdx.x & 127;
  __shared__ float st[CIN];
  __shared__ float red[4];
  int tid = threadIdx.x;   // 256
  if (tid < CIN) st[tid] = styles[b * CIN + tid];
  __syncthreads();
  const float* wr = weight + (size_t)co * (CIN * NTAPS);  // [cin][27] for this cout
  float ss = 0.f;
  for (int o = tid; o < CIN * NTAPS; o += 256) {
    float v = wr[o] * st[o / NTAPS];
    ss += v * v;
  }
#pragma unroll
  for (int off = 32; off > 0; off >>= 1) ss += __shfl_down(ss, off);
  if ((tid & 63) == 0) red[tid >> 6] = ss;
  __syncthreads();
  float d = rsqrtf(red[0] + red[1] + red[2] + red[3] + 1e-8f);
  for (int o = tid; o < CIN * NTAPS; o += 256) {
    int t = o >> 7;
    int cin = o & 127;
    float v = wr[cin * NTAPS + t] * st[cin] * d;
    int cc = cin >> 5, cl = cin & 31;
    wmod[((((size_t)(b * 4 + cc) * COUT + co) * NTAPS + t) << 5) + cl] =
        __float2bfloat16(v);
  }
}

// ---- kernel 3: x f32 [b][cin][sp] -> xt bf16 [b][cc][sp][cin32] ----
__global__ __launch_bounds__(256)
void k_xt(const float* __restrict__ x, __hip_bfloat16* __restrict__ xt) {
  __shared__ __align__(16) float ts[32][257];   // 32.9 KB, pad -> 2-way max
  int t = threadIdx.x;
  int blk = blockIdx.x;            // 8 b * 4 cc * 128 spchunks
  int b = blk >> 9, cc = (blk >> 7) & 3, sp0 = (blk & 127) << 8;
  const float* xb = x + (size_t)b * CIN * NSP + (size_t)cc * 32 * NSP + sp0;
#pragma unroll
  for (int i = 0; i < 8; i++) {
    int q = i * 256 + t;
    int cin = q >> 6, f4 = q & 63;
    float4 v = *(const float4*)(xb + (size_t)cin * NSP + f4 * 4);
    *(float4*)&ts[cin][f4 * 4] = v;
  }
  __syncthreads();
  __hip_bfloat16* ob = xt + ((size_t)(b * 4 + cc) * NSP + sp0) * 32;
#pragma unroll
  for (int j = 0; j < 4; j++) {
    int chunk = j * 256 + t;
    int sp_l = chunk >> 2, q = chunk & 3;
    union { bf16x8 v; __hip_bfloat16 h[8]; } u;
#pragma unroll
    for (int k = 0; k < 8; k++) u.h[k] = __float2bfloat16(ts[q * 8 + k][sp_l]);
    *(bf16x8*)(ob + (size_t)sp_l * 32 + q * 8) = u.v;
  }
}

// ---------------- kernel 4: implicit-GEMM conv + bias + lrelu*sqrt(2) ----------------
// R9/R11 structure: 256 thr = 4 waves, each wave = one 32-cout quarter x FULL 128 sp
// (16 MFMA : 2 A-chunks per tap). LDS dbuf; A 4-deep (R11); NEW: B 3-slot rotation,
// B(t+2) issued at top of tap t -> ~2-tap (600+ cy) cover over LDS-port queueing.
// b = blk&7 pins one batch per XCD.
__global__ __launch_bounds__(256, 2)
void k_conv(const char* __restrict__ ws,
            const float* __restrict__ bias,
            float* __restrict__ out) {
  extern __shared__ __align__(16) char xs[];   // 2 * BUFB

  int tid = threadIdx.x;
  int lane = tid & 63, w = tid >> 6;
  int l15 = lane & 15, g = lane >> 4;
  int blk = blockIdx.x;
  int b = blk & 7;                 // one batch per XCD (wmod/xt L2 locality)
  int tile = blk >> 3;             // 16 tz * 16 ty, sequential per XCD
  int z0 = (tile >> 4) * 2, y0 = (tile & 15) * 2;

  // zero column init, both buffers: 16 rows x 64 B at row offset 2048
  {
    int r16 = tid >> 4, c16 = (tid & 15) * 4;
    *(int*)&xs[r16 * ROWB + 2048 + c16] = 0;
    *(int*)&xs[BUFB + r16 * ROWB + 2048 + c16] = 0;
  }

  // ---- staging tables: 2048 16-B chunks per cc, 8 iters x 256 thr ----
  int soff[8], sdst[8], svalid[8];
#pragma unroll
  for (int i = 0; i < 8; i++) {
    int c = i * 256 + tid;
    int zy = c >> 7;                       // wave-uniform
    int hz = zy >> 2, hy = zy & 3;
    int zz = z0 + hz - 1, yy = y0 + hy - 1;
    svalid[i] = ((unsigned)zz < NRES) & ((unsigned)yy < NRES);
    int p = c & 127, hx = p >> 2, pos = p & 3;
    int q = pos ^ ((hx >> 1) & 3);         // pre-swizzled global source (rule #21)
    soff[i] = (zz * 1024 + yy * 32 + hx) * 4 + q;   // 16-B units within xt[b][cc]
    sdst[i] = zy * ROWB + (p >> 6) * 1024;          // linear wave-uniform LDS dest
  }

  // ---- fragment LDS addrs: vaddr[ni][tx], OOB x -> zero column (hx=32) ----
  int vaddr[8][3];
#pragma unroll
  for (int ni = 0; ni < 8; ni++) {
    int row = (ni >> 2) * 4 + ((ni >> 1) & 1);   // dz*4 + dy
    int dx = (ni & 1) * 16 + l15;
#pragma unroll
    for (int tx = 0; tx < 3; tx++) {
      int hx = dx + tx - 1;
      int hxc = ((unsigned)hx > 31u) ? 32 : hx;
      int pos = g ^ ((hxc >> 1) & 3);
      vaddr[ni][tx] = row * ROWB + hxc * 64 + pos * 16;
    }
  }

  // ---- A chunk bases: chunk idx = ((b*4+cc)*128 + cout)*108 + tap*4 + g ----
  const bf16x8* ap = (const bf16x8*)(ws + WM_OFF);
  int abase[2];
#pragma unroll
  for (int mi = 0; mi < 2; mi++)
    abase[mi] = (w * 32 + mi * 16 + l15) * 108 + g;

  f32x4 acc[2][8];
#pragma unroll
  for (int mi = 0; mi < 2; mi++)
#pragma unroll
    for (int ni = 0; ni < 8; ni++) acc[mi][ni] = (f32x4){0.f, 0.f, 0.f, 0.f};

  const char* zpg = ws + ZP_OFF;
  const char* xtb = ws + XT_OFF + (size_t)b * (4 * NSP * 64);

  auto stage = [&](char* dst, const char* xtc) {
#pragma unroll
    for (int i = 0; i < 8; i++) {
      const char* src = svalid[i] ? (xtc + ((size_t)(unsigned)soff[i] << 4))
                                  : (zpg + lane * 16);
      __builtin_amdgcn_global_load_lds((gu32*)src, (lu32*)(dst + sdst[i]), 16, 0, 0);
    }
  };

  // prologue: stage cc=0 into buf0; barrier drains it (once) + zero-col visible
  stage(xs, xtb);
  __syncthreads();

#pragma unroll 1
  for (int cc = 0; cc < 4; cc++) {
    char* cur = xs + (cc & 1) * BUFB;
    int sab = ((b * 4 + cc) * 128) * 108;
    int abc0 = sab + abase[0], abc1 = sab + abase[1];

    bf16x8 A[4][2], B[3][8];
    // deep prologue BEFORE STAGE: A taps 0..3 (vmcnt in-order: their waits never
    // drain staging) + B taps 0,1 (lgkm, 2-tap depth from the start)
#pragma unroll
    for (int pt = 0; pt < 4; pt++) {
      A[pt][0] = ap[abc0 + pt * 4];
      A[pt][1] = ap[abc1 + pt * 4];
    }
#pragma unroll
    for (int pt = 0; pt < 2; pt++) {      // taps 0,1: tz=ty=0 -> lit=0, tx=pt
#pragma unroll
      for (int j = 0; j < 8; j++)
        B[pt][j] = *(const bf16x8*)(cur + vaddr[j][pt]);
    }
    __builtin_amdgcn_sched_barrier(0);     // pin: prologue loads before staging
    if (cc < 3)
      stage(xs + ((cc + 1) & 1) * BUFB, xtb + (size_t)(cc + 1) * (NSP * 64));
    __builtin_amdgcn_sched_barrier(0);     // pin: staging before tap loop

#pragma unroll
    for (int t = 0; t < NTAPS; t++) {
      const int s = t & 3;                 // A slot (4-deep)
      const int sb = t % 3;                // B slot (3-deep)
      // B(t+2) two-tap-ahead prefetch into slot (t+2)%3 (free: live = t%3,(t+1)%3)
      if (t + 2 < NTAPS) {
        const int t2 = t + 2;
        const int tx2 = t2 % 3;
        const int lit2 = ((t2 / 9) * 4 + (t2 / 3) % 3) * ROWB;
#pragma unroll
        for (int j = 0; j < 8; j++)
          B[t2 % 3][j] = *(const bf16x8*)(cur + vaddr[j][tx2] + lit2);
      }
      __builtin_amdgcn_s_setprio(1);
#pragma unroll
      for (int mi = 0; mi < 2; mi++) {
        acc[mi][0] = __builtin_amdgcn_mfma_f32_16x16x32_bf16(A[s][mi], B[sb][0], acc[mi][0], 0, 0, 0);
        acc[mi][1] = __builtin_amdgcn_mfma_f32_16x16x32_bf16(A[s][mi], B[sb][1], acc[mi][1], 0, 0, 0);
        acc[mi][2] = __builtin_amdgcn_mfma_f32_16x16x32_bf16(A[s][mi], B[sb][2], acc[mi][2], 0, 0, 0);
        acc[mi][3] = __builtin_amdgcn_mfma_f32_16x16x32_bf16(A[s][mi], B[sb][3], acc[mi][3], 0, 0, 0);
        acc[mi][4] = __builtin_amdgcn_mfma_f32_16x16x32_bf16(A[s][mi], B[sb][4], acc[mi][4], 0, 0, 0);
        acc[mi][5] = __builtin_amdgcn_mfma_f32_16x16x32_bf16(A[s][mi], B[sb][5], acc[mi][5], 0, 0, 0);
        acc[mi][6] = __builtin_amdgcn_mfma_f32_16x16x32_bf16(A[s][mi], B[sb][6], acc[mi][6], 0, 0, 0);
        acc[mi][7] = __builtin_amdgcn_mfma_f32_16x16x32_bf16(A[s][mi], B[sb][7], acc[mi][7], 0, 0, 0);
      }
      __builtin_amdgcn_s_setprio(0);
      // A(t+4) issue at bottom of tap t into slot s (just consumed)
      if (t + 4 < NTAPS) {
        A[s][0] = ap[abc0 + (t + 4) * 4];
        A[s][1] = ap[abc1 + (t + 4) * 4];
      }
    }
    if (cc < 3) __syncthreads();   // staged loads ~27 taps old -> drain free
  }

  // epilogue: cout = w*32 + mi*16 + g*4 + r ; sp = (z0+dz, y0+dy, dx)
  size_t ob = ((size_t)(b * COUT + w * 32 + g * 4)) * NSP +
              (size_t)z0 * 1024 + (size_t)y0 * 32;
#pragma unroll
  for (int mi = 0; mi < 2; mi++) {
    float4 bsv = *(const float4*)(bias + w * 32 + mi * 16 + g * 4);
    float bs[4] = {bsv.x, bsv.y, bsv.z, bsv.w};
#pragma unroll
    for (int ni = 0; ni < 8; ni++) {
      int spo = (ni >> 2) * 1024 + ((ni >> 1) & 1) * 32 + (ni & 1) * 16 + l15;
#pragma unroll
      for (int r = 0; r < 4; r++) {
        float v = acc[mi][ni][r] + bs[r];
        v = (v >= 0.f ? v : v * 0.2f) * 1.41421356237309515f;
        out[ob + (size_t)(mi * 16 + r) * NSP + spo] = v;
      }
    }
  }
}

extern "C" void kernel_launch(void* const* d_in, const int* in_sizes, int n_in,
                              void* d_out, int out_size, void* d_ws, size_t ws_size,
                              hipStream_t stream) {
  const float* x      = (const float*)d_in[0];
  const float* w      = (const float*)d_in[1];
  const float* weight = (const float*)d_in[2];
  const float* aw     = (const float*)d_in[3];
  const float* ab     = (const float*)d_in[4];
  const float* bias   = (const float*)d_in[5];
  float* out = (float*)d_out;

  float* styles = (float*)d_ws;
  float* zeropad = (float*)((char*)d_ws + ZP_OFF);
  __hip_bfloat16* xt = (__hip_bfloat16*)((char*)d_ws + XT_OFF);
  __hip_bfloat16* wmod = (__hip_bfloat16*)((char*)d_ws + WM_OFF);

  k_styles<<<8, 128, 0, stream>>>(w, aw, ab, styles, zeropad);
  k_wmod<<<8 * 128, 256, 0, stream>>>(weight, styles, wmod);
  k_xt<<<8 * 4 * 128, 256, 0, stream>>>(x, xt);
  k_conv<<<8 * 256, 256, 2 * BUFB, stream>>>((const char*)d_ws, bias, out);
}